// Round 1
// baseline (278.176 us; speedup 1.0000x reference)
//
#include <hip/hip_runtime.h>
#include <hip/hip_fp16.h>
#include <math.h>

#define N_ATOMS 512
#define F_DIM   128
#define K_RBF   301
#define NLAYER  3
#define GAMMA_C 10.0f
#define LOG2_C  0.6931471805599453f

// Filter lookup table: w_l(d) sampled at step TAB_H; max d = 10*sqrt(3) = 17.32
#define TAB_H     0.01f
#define TAB_INVH  100.0f
#define TAB_ROWS  1768          // 221 * 8, covers up to 17.67
#define RPB       8             // table rows emitted per task (computes RPB+1)
#define NGROUPS   (TAB_ROWS / RPB)          // 221
#define NTASKS    (NGROUPS * NLAYER)        // 663 (row-group, layer) tasks
#define NBBLK2    ((NTASKS + 1) / 2)        // 332 build blocks, 2 tasks each
#define ROW_BYTES 512           // 64 f-pairs * 8 B (uint2 per pair)

__device__ __forceinline__ float ssp(float x) {
    float ax = fabsf(x);
    return fmaxf(x, 0.0f) + log1pf(expf(-ax)) - LOG2_C;
}
__device__ __forceinline__ __half2 u2h2(unsigned u) {
    union { unsigned u; __half2 h; } c; c.u = u; return c.h;
}
__device__ __forceinline__ unsigned h22u(__half2 h) {
    union { unsigned u; __half2 h; } c; c.h = h; return c.u;
}

// ---------------------------------------------------------------------------
// Fused prep + table build.  grid: (512 + 332) x 256   (round-4/7 proven)
// Also zeroes the grid-barrier counters used by convnode3.
__global__ void __launch_bounds__(256)
prep_build(const int* __restrict__ x, const float* __restrict__ r,
           const float* __restrict__ emb,
           const float* __restrict__ aw_W, const float* __restrict__ aw_b,
           const float* __restrict__ cf_W1, const float* __restrict__ cf_b1,
           const float* __restrict__ cf_W2, const float* __restrict__ cf_b2,
           uint2* __restrict__ dpk, unsigned* __restrict__ opk,
           uint2* __restrict__ ptab, unsigned* __restrict__ sync) {
    __shared__ float hs[F_DIM];
    __shared__ float os[F_DIM];
    __shared__ float e_s[2][RPB + 1][34];
    __shared__ float w1_s[2][F_DIM][12];

    if (blockIdx.x == 0 && threadIdx.x < 8) sync[threadIdx.x] = 0u;

    if (blockIdx.x < N_ATOMS) {
        // ---- prep path: distances + embedding + layer-0 atomwise ----
        int i = blockIdx.x;
        int t = threadIdx.x;
        float rx = r[i * 3 + 0], ry = r[i * 3 + 1], rz = r[i * 3 + 2];
        if (t < F_DIM) hs[t] = emb[x[i] * F_DIM + t];
        for (int j = t; j < N_ATOMS; j += 256) {
            float dx = rx - r[j * 3 + 0];
            float dy = ry - r[j * 3 + 1];
            float dz = rz - r[j * 3 + 2];
            float d  = sqrtf(dx * dx + dy * dy + dz * dz);
            float xb = d * TAB_INVH;
            int   b  = ::min((int)xb, TAB_ROWS - 2);
            float fr = xb - (float)b;
            __half fh = __float2half(fr);
            dpk[i * N_ATOMS + j] = make_uint2((unsigned)b * ROW_BYTES,
                                              h22u(__halves2half2(fh, fh)));
        }
        __syncthreads();
        if (t < F_DIM) {
            float acc = aw_b[t];
            for (int g = 0; g < F_DIM; ++g) acc = fmaf(hs[g], aw_W[g * F_DIM + t], acc);
            os[t] = acc;
        }
        __syncthreads();
        if (t < F_DIM / 2)
            opk[i * 64 + t] = h22u(__halves2half2(__float2half(os[2 * t]),
                                                  __float2half(os[2 * t + 1])));
        return;
    }

    // ---- build path: 2 (row-group, layer) tasks per block ----
    int u = threadIdx.x >> 7;
    int f = threadIdx.x & 127;
    int task = (blockIdx.x - N_ATOMS) * 2 + u;
    bool valid = task < NTASKS;
    task = valid ? task : NTASKS - 1;
    int l    = task / NGROUPS;
    int row0 = (task % NGROUPS) * RPB;

    float dlo = row0 * TAB_H;
    float dhi = (row0 + RPB) * TAB_H;
    // Gaussian window: exp(-10*1.45^2) ~ 7.6e-10 truncation
    int k0 = ::max(0, (int)ceilf((dlo - 1.45f) * 10.0f));
    int k1 = ::min(K_RBF - 1, (int)floorf((dhi + 1.45f) * 10.0f));
    int kw = k1 - k0 + 1;

    for (int idx = f; idx < (RPB + 1) * kw; idx += F_DIM) {
        int rr = idx / kw, kk = idx % kw;
        float dv = (row0 + rr) * TAB_H;
        float tt = dv - 0.1f * (float)(k0 + kk);
        e_s[u][rr][kk] = expf(-GAMMA_C * tt * tt);
    }
    __syncthreads();

    const float* W1 = cf_W1 + l * K_RBF * F_DIM;
    float b1v = cf_b1[l * F_DIM + f];
    float acc[RPB + 1];
#pragma unroll
    for (int rr = 0; rr <= RPB; ++rr) acc[rr] = b1v;
    for (int kk = 0; kk < kw; ++kk) {
        float w1v = W1[(k0 + kk) * F_DIM + f];
#pragma unroll
        for (int rr = 0; rr <= RPB; ++rr) acc[rr] = fmaf(e_s[u][rr][kk], w1v, acc[rr]);
    }
#pragma unroll
    for (int rr = 0; rr <= RPB; ++rr) w1_s[u][f][rr] = ssp(acc[rr]);
    __syncthreads();

    const float* W2 = cf_W2 + l * F_DIM * F_DIM;
    float b2v = cf_b2[l * F_DIM + f];
    float acc2[RPB + 1];
#pragma unroll
    for (int rr = 0; rr <= RPB; ++rr) acc2[rr] = b2v;
    for (int g = 0; g < F_DIM; ++g) {
        float w2v = W2[g * F_DIM + f];
        float4 wa = *(const float4*)&w1_s[u][g][0];
        float4 wb = *(const float4*)&w1_s[u][g][4];
        float  wc = w1_s[u][g][8];
        acc2[0] = fmaf(wa.x, w2v, acc2[0]);
        acc2[1] = fmaf(wa.y, w2v, acc2[1]);
        acc2[2] = fmaf(wa.z, w2v, acc2[2]);
        acc2[3] = fmaf(wa.w, w2v, acc2[3]);
        acc2[4] = fmaf(wb.x, w2v, acc2[4]);
        acc2[5] = fmaf(wb.y, w2v, acc2[5]);
        acc2[6] = fmaf(wb.z, w2v, acc2[6]);
        acc2[7] = fmaf(wb.w, w2v, acc2[7]);
        acc2[8] = fmaf(wc,   w2v, acc2[8]);
    }
    float o9[RPB + 1];
#pragma unroll
    for (int rr = 0; rr <= RPB; ++rr) o9[rr] = ssp(acc2[rr]);

    // pack via same-wave shfl with lane f^1; even lanes write pair p=f>>1
    if (valid) {
        int p = f >> 1;
        bool odd = (f & 1);
#pragma unroll
        for (int rr = 0; rr < RPB; ++rr) {
            float t0 = o9[rr];
            float dt = o9[rr + 1] - o9[rr];
            float ot0 = __shfl_xor(t0, 1, 64);
            float odt = __shfl_xor(dt, 1, 64);
            if (!odd) {
                uint2 v = make_uint2(
                    h22u(__halves2half2(__float2half(t0), __float2half(ot0))),
                    h22u(__halves2half2(__float2half(dt), __float2half(odt))));
                ptab[((size_t)l * TAB_ROWS + row0 + rr) * 64 + p] = v;
            }
        }
    }
}

// ---------------------------------------------------------------------------
// Device-scope grid barrier.  Single-use counter per barrier (no reset, no
// generation).  Safe because grid == 512 == 2 blocks/CU x 256 CUs, forced
// co-resident by __launch_bounds__(512, 4).  prep_build zeroes the counters.
__device__ __forceinline__ void grid_barrier(unsigned* cnt) {
    __syncthreads();   // drains each wave's vmcnt before arrival
    if (threadIdx.x == 0) {
        __hip_atomic_fetch_add(cnt, 1u, __ATOMIC_ACQ_REL, __HIP_MEMORY_SCOPE_AGENT);
        while (__hip_atomic_load(cnt, __ATOMIC_ACQUIRE, __HIP_MEMORY_SCOPE_AGENT)
               < (unsigned)N_ATOMS)
            __builtin_amdgcn_s_sleep(2);
    }
    __syncthreads();
}

// ---------------------------------------------------------------------------
// Fused 3-layer conv + node (+ next atomwise / output head).  grid: 512 x 512
// One launch for all layers; dpk row and h stay resident in LDS across
// layers; h global array eliminated.  Per-layer math identical to the
// previous per-layer kernel (bit-identical reduction order).
__global__ void __launch_bounds__(512, 4)
convnode3(const uint2* __restrict__ dpk, const int* __restrict__ x,
          const float* __restrict__ emb, const uint2* __restrict__ ptab,
          const float* __restrict__ n_W1, const float* __restrict__ n_b1,
          const float* __restrict__ n_W2, const float* __restrict__ n_b2,
          const float* __restrict__ aw_W, const float* __restrict__ aw_b,
          unsigned* __restrict__ opkA, unsigned* __restrict__ opkB,
          const float* __restrict__ oW1, const float* __restrict__ ob1,
          const float* __restrict__ oW2, const float* __restrict__ ob2,
          float* __restrict__ out, unsigned* __restrict__ sync) {
    int i  = blockIdx.x;
    int t  = threadIdx.x;
    int p2 = t & 31;
    int jc = t >> 5;            // 0..15

    __shared__ __align__(16) uint2 ds[N_ATOMS];          // 4 KB, lives all layers
    __shared__ __align__(16) float redbuf[16 * 32 * 4];  // 8 KB, multi-use
    __shared__ __align__(16) float cs[F_DIM];
    __shared__ __align__(16) float t1s[F_DIM];
    __shared__ __align__(16) float hs[F_DIM];            // lives all layers

    ds[t] = dpk[i * N_ATOMS + t];
    if (t < F_DIM) hs[t] = emb[x[i] * F_DIM + t];
    __syncthreads();

    for (int l = 0; l < NLAYER; ++l) {
        const unsigned* opk_in = (l & 1) ? opkB : opkA;
        unsigned*       opk_out = (l & 1) ? opkA : opkB;

        // ---- conv: 4 features/lane, 32 j per jc group ----
        const char*  T  = (const char*)(ptab + (size_t)l * TAB_ROWS * 64) + p2 * 16;
        const uint2* ob = (const uint2*)opk_in + p2;     // + j*32 below

        float4 acc = make_float4(0.0f, 0.0f, 0.0f, 0.0f);
        int j0 = jc * 32;
#pragma unroll 4
        for (int jj = 0; jj < 32; ++jj) {
            int j = j0 + jj;
            uint2 e = ds[j];                     // broadcast: uniform per half-wave
            uint4 tv = *(const uint4*)(T + e.x); // {t0 a, dt a, t0 b, dt b}
            uint2 ohu = ob[j * 32];              // features 4p2..4p2+3 of o_j
            __half2 fr2 = u2h2(e.y);
            __half2 wa = __hfma2(fr2, u2h2(tv.y), u2h2(tv.x));
            __half2 wb = __hfma2(fr2, u2h2(tv.w), u2h2(tv.z));
            __half2 oa = u2h2(ohu.x);
            __half2 obh = u2h2(ohu.y);
            acc.x = fmaf(__half2float(__low2half(wa)),  __half2float(__low2half(oa)),  acc.x);
            acc.y = fmaf(__half2float(__high2half(wa)), __half2float(__high2half(oa)), acc.y);
            acc.z = fmaf(__half2float(__low2half(wb)),  __half2float(__low2half(obh)), acc.z);
            acc.w = fmaf(__half2float(__high2half(wb)), __half2float(__high2half(obh)), acc.w);
        }
        *(float4*)&redbuf[(jc * 32 + p2) * 4] = acc;
        __syncthreads();
        if (t < 32) {
            float4 s = *(const float4*)&redbuf[t * 4];
#pragma unroll
            for (int q = 1; q < 16; ++q) {
                float4 v = *(const float4*)&redbuf[(q * 32 + t) * 4];
                s.x += v.x; s.y += v.y; s.z += v.z; s.w += v.w;
            }
            *(float4*)&cs[4 * t] = s;
        }
        __syncthreads();

        // ---- node MLP, phase A: t1s = ssp(cs @ W1 + b1), 4-way g-split ----
        {
            int q = t >> 7, f = t & 127;         // q in [0,4), 32 g each
            const float* W1 = n_W1 + l * F_DIM * F_DIM;
            float a = 0.0f;
            int g0 = q * 32;
            for (int g = 0; g < 32; ++g) a = fmaf(cs[g0 + g], W1[(g0 + g) * F_DIM + f], a);
            redbuf[q * F_DIM + f] = a;
        }
        __syncthreads();
        if (t < F_DIM) {
            float a = redbuf[t] + redbuf[F_DIM + t] + redbuf[2 * F_DIM + t]
                    + redbuf[3 * F_DIM + t] + n_b1[l * F_DIM + t];
            t1s[t] = ssp(a);
        }
        __syncthreads();

        // ---- phase B: hs += t1s @ W2 + b2 (h never leaves LDS) ----
        {
            int q = t >> 7, f = t & 127;
            const float* W2 = n_W2 + l * F_DIM * F_DIM;
            float a = 0.0f;
            int g0 = q * 32;
            for (int g = 0; g < 32; ++g) a = fmaf(t1s[g0 + g], W2[(g0 + g) * F_DIM + f], a);
            redbuf[q * F_DIM + f] = a;
        }
        __syncthreads();
        if (t < F_DIM) {
            float a2 = redbuf[t] + redbuf[F_DIM + t] + redbuf[2 * F_DIM + t]
                     + redbuf[3 * F_DIM + t] + n_b2[l * F_DIM + t];
            hs[t] = hs[t] + a2;
        }
        __syncthreads();

        if (l < NLAYER - 1) {
            // ---- phase C: next layer's atom-wise linear, packed half2 ----
            {
                int q = t >> 7, f = t & 127;
                const float* W = aw_W + (l + 1) * F_DIM * F_DIM;
                float a = 0.0f;
                int g0 = q * 32;
                for (int g = 0; g < 32; ++g) a = fmaf(hs[g0 + g], W[(g0 + g) * F_DIM + f], a);
                redbuf[q * F_DIM + f] = a;
            }
            __syncthreads();
            if (t < F_DIM) {
                t1s[t] = redbuf[t] + redbuf[F_DIM + t] + redbuf[2 * F_DIM + t]
                       + redbuf[3 * F_DIM + t] + aw_b[(l + 1) * F_DIM + t];
            }
            __syncthreads();
            if (t < F_DIM / 2)
                opk_out[i * 64 + t] = h22u(__halves2half2(__float2half(t1s[2 * t]),
                                                          __float2half(t1s[2 * t + 1])));
            // all blocks must finish writing opk_out before next layer's conv
            grid_barrier(&sync[l]);
        } else {
            // ---- output head: out[i] = ssp(hs @ oW1 + ob1) @ oW2 + ob2 ----
            {
                int q = t >> 5, f = t & 31;      // q in [0,16), 8 g each
                float a = 0.0f;
                int g0 = q * 8;
                for (int g = 0; g < 8; ++g) a = fmaf(hs[g0 + g], oW1[(g0 + g) * 32 + f], a);
                redbuf[q * 32 + f] = a;
            }
            __syncthreads();
            float val = 0.0f;
            if (t < 32) {
                float a = ob1[t];
#pragma unroll
                for (int q = 0; q < 16; ++q) a += redbuf[q * 32 + t];
                val = ssp(a) * oW2[t];
            }
#pragma unroll
            for (int off = 16; off > 0; off >>= 1) val += __shfl_xor(val, off, 64);
            if (t == 0) out[i] = val + ob2[0];
        }
    }
}

// ---------------------------------------------------------------------------
extern "C" void kernel_launch(void* const* d_in, const int* in_sizes, int n_in,
                              void* d_out, int out_size, void* d_ws, size_t ws_size,
                              hipStream_t stream) {
    const int*   x     = (const int*)  d_in[0];
    const float* r     = (const float*)d_in[1];
    const float* emb   = (const float*)d_in[2];
    const float* aw_W  = (const float*)d_in[3];
    const float* aw_b  = (const float*)d_in[4];
    const float* cf_W1 = (const float*)d_in[5];
    const float* cf_b1 = (const float*)d_in[6];
    const float* cf_W2 = (const float*)d_in[7];
    const float* cf_b2 = (const float*)d_in[8];
    const float* n_W1  = (const float*)d_in[9];
    const float* n_b1  = (const float*)d_in[10];
    const float* n_W2  = (const float*)d_in[11];
    const float* n_b2  = (const float*)d_in[12];
    const float* oW1   = (const float*)d_in[13];
    const float* ob1   = (const float*)d_in[14];
    const float* oW2   = (const float*)d_in[15];
    const float* ob2   = (const float*)d_in[16];
    float* out = (float*)d_out;

    char* ws = (char*)d_ws;
    uint2*    dpk  = (uint2*)ws;    ws += (size_t)N_ATOMS * N_ATOMS * 8;       // 2 MB
    unsigned* opkA = (unsigned*)ws; ws += (size_t)N_ATOMS * (F_DIM / 2) * 4;   // 128 KB
    unsigned* opkB = (unsigned*)ws; ws += (size_t)N_ATOMS * (F_DIM / 2) * 4;   // 128 KB
    uint2*    ptab = (uint2*)ws;    ws += (size_t)NLAYER * TAB_ROWS * 64 * 8;  // 2.7 MB
    unsigned* sync = (unsigned*)ws;                                            // 32 B

    prep_build<<<N_ATOMS + NBBLK2, 256, 0, stream>>>(
        x, r, emb, aw_W, aw_b, cf_W1, cf_b1, cf_W2, cf_b2, dpk, opkA, ptab, sync);
    convnode3<<<N_ATOMS, 512, 0, stream>>>(
        dpk, x, emb, ptab, n_W1, n_b1, n_W2, n_b2, aw_W, aw_b,
        opkA, opkB, oW1, ob1, oW2, ob2, out, sync);
}

// Round 2
// 157.006 us; speedup vs baseline: 1.7718x; 1.7718x over previous
//
#include <hip/hip_runtime.h>
#include <hip/hip_fp16.h>
#include <math.h>

#define N_ATOMS 512
#define F_DIM   128
#define K_RBF   301
#define NLAYER  3
#define GAMMA_C 10.0f
#define LOG2_C  0.6931471805599453f

// Filter lookup table: w_l(d) sampled at step TAB_H; max d = 10*sqrt(3) = 17.32
#define TAB_H     0.01f
#define TAB_INVH  100.0f
#define TAB_ROWS  1768          // 221 * 8, covers up to 17.67
#define RPB       8             // table rows emitted per task (computes RPB+1)
#define NGROUPS   (TAB_ROWS / RPB)          // 221
#define NTASKS    (NGROUPS * NLAYER)        // 663 (row-group, layer) tasks
#define NBBLK2    ((NTASKS + 1) / 2)        // 332 build blocks, 2 tasks each
#define ROW_BYTES 512           // 64 f-pairs * 8 B (uint2 per pair)

#define JSPLIT  4               // conv j-dimension split
#define JPB     (N_ATOMS / JSPLIT)   // 128 j per conv block

__device__ __forceinline__ float ssp(float x) {
    float ax = fabsf(x);
    return fmaxf(x, 0.0f) + log1pf(expf(-ax)) - LOG2_C;
}
__device__ __forceinline__ __half2 u2h2(unsigned u) {
    union { unsigned u; __half2 h; } c; c.u = u; return c.h;
}
__device__ __forceinline__ unsigned h22u(__half2 h) {
    union { unsigned u; __half2 h; } c; c.h = h; return c.u;
}

// ---------------------------------------------------------------------------
// Fused prep + table build.  grid: (512 + 332) x 256   (round-0 proven form)
__global__ void __launch_bounds__(256)
prep_build(const int* __restrict__ x, const float* __restrict__ r,
           const float* __restrict__ emb,
           const float* __restrict__ aw_W, const float* __restrict__ aw_b,
           const float* __restrict__ cf_W1, const float* __restrict__ cf_b1,
           const float* __restrict__ cf_W2, const float* __restrict__ cf_b2,
           uint2* __restrict__ dpk, float* __restrict__ h,
           unsigned* __restrict__ opk, uint2* __restrict__ ptab) {
    __shared__ float hs[F_DIM];
    __shared__ float os[F_DIM];
    __shared__ float e_s[2][RPB + 1][34];
    __shared__ float w1_s[2][F_DIM][12];

    if (blockIdx.x < N_ATOMS) {
        // ---- prep path: distances + embedding + layer-0 atomwise ----
        int i = blockIdx.x;
        int t = threadIdx.x;
        float rx = r[i * 3 + 0], ry = r[i * 3 + 1], rz = r[i * 3 + 2];
        if (t < F_DIM) {
            float hv = emb[x[i] * F_DIM + t];
            h[i * F_DIM + t] = hv;
            hs[t] = hv;
        }
        for (int j = t; j < N_ATOMS; j += 256) {
            float dx = rx - r[j * 3 + 0];
            float dy = ry - r[j * 3 + 1];
            float dz = rz - r[j * 3 + 2];
            float d  = sqrtf(dx * dx + dy * dy + dz * dz);
            float xb = d * TAB_INVH;
            int   b  = ::min((int)xb, TAB_ROWS - 2);
            float fr = xb - (float)b;
            __half fh = __float2half(fr);
            dpk[i * N_ATOMS + j] = make_uint2((unsigned)b * ROW_BYTES,
                                              h22u(__halves2half2(fh, fh)));
        }
        __syncthreads();
        if (t < F_DIM) {
            float acc = aw_b[t];
            for (int g = 0; g < F_DIM; ++g) acc = fmaf(hs[g], aw_W[g * F_DIM + t], acc);
            os[t] = acc;
        }
        __syncthreads();
        if (t < F_DIM / 2)
            opk[i * 64 + t] = h22u(__halves2half2(__float2half(os[2 * t]),
                                                  __float2half(os[2 * t + 1])));
        return;
    }

    // ---- build path: 2 (row-group, layer) tasks per block ----
    int u = threadIdx.x >> 7;
    int f = threadIdx.x & 127;
    int task = (blockIdx.x - N_ATOMS) * 2 + u;
    bool valid = task < NTASKS;
    task = valid ? task : NTASKS - 1;
    int l    = task / NGROUPS;
    int row0 = (task % NGROUPS) * RPB;

    float dlo = row0 * TAB_H;
    float dhi = (row0 + RPB) * TAB_H;
    // Gaussian window: exp(-10*1.45^2) ~ 7.6e-10 truncation
    int k0 = ::max(0, (int)ceilf((dlo - 1.45f) * 10.0f));
    int k1 = ::min(K_RBF - 1, (int)floorf((dhi + 1.45f) * 10.0f));
    int kw = k1 - k0 + 1;

    for (int idx = f; idx < (RPB + 1) * kw; idx += F_DIM) {
        int rr = idx / kw, kk = idx % kw;
        float dv = (row0 + rr) * TAB_H;
        float tt = dv - 0.1f * (float)(k0 + kk);
        e_s[u][rr][kk] = expf(-GAMMA_C * tt * tt);
    }
    __syncthreads();

    const float* W1 = cf_W1 + l * K_RBF * F_DIM;
    float b1v = cf_b1[l * F_DIM + f];
    float acc[RPB + 1];
#pragma unroll
    for (int rr = 0; rr <= RPB; ++rr) acc[rr] = b1v;
    for (int kk = 0; kk < kw; ++kk) {
        float w1v = W1[(k0 + kk) * F_DIM + f];
#pragma unroll
        for (int rr = 0; rr <= RPB; ++rr) acc[rr] = fmaf(e_s[u][rr][kk], w1v, acc[rr]);
    }
#pragma unroll
    for (int rr = 0; rr <= RPB; ++rr) w1_s[u][f][rr] = ssp(acc[rr]);
    __syncthreads();

    const float* W2 = cf_W2 + l * F_DIM * F_DIM;
    float b2v = cf_b2[l * F_DIM + f];
    float acc2[RPB + 1];
#pragma unroll
    for (int rr = 0; rr <= RPB; ++rr) acc2[rr] = b2v;
    for (int g = 0; g < F_DIM; ++g) {
        float w2v = W2[g * F_DIM + f];
        float4 wa = *(const float4*)&w1_s[u][g][0];
        float4 wb = *(const float4*)&w1_s[u][g][4];
        float  wc = w1_s[u][g][8];
        acc2[0] = fmaf(wa.x, w2v, acc2[0]);
        acc2[1] = fmaf(wa.y, w2v, acc2[1]);
        acc2[2] = fmaf(wa.z, w2v, acc2[2]);
        acc2[3] = fmaf(wa.w, w2v, acc2[3]);
        acc2[4] = fmaf(wb.x, w2v, acc2[4]);
        acc2[5] = fmaf(wb.y, w2v, acc2[5]);
        acc2[6] = fmaf(wb.z, w2v, acc2[6]);
        acc2[7] = fmaf(wb.w, w2v, acc2[7]);
        acc2[8] = fmaf(wc,   w2v, acc2[8]);
    }
    float o9[RPB + 1];
#pragma unroll
    for (int rr = 0; rr <= RPB; ++rr) o9[rr] = ssp(acc2[rr]);

    // pack via same-wave shfl with lane f^1; even lanes write pair p=f>>1
    if (valid) {
        int p = f >> 1;
        bool odd = (f & 1);
#pragma unroll
        for (int rr = 0; rr < RPB; ++rr) {
            float t0 = o9[rr];
            float dt = o9[rr + 1] - o9[rr];
            float ot0 = __shfl_xor(t0, 1, 64);
            float odt = __shfl_xor(dt, 1, 64);
            if (!odd) {
                uint2 v = make_uint2(
                    h22u(__halves2half2(__float2half(t0), __float2half(ot0))),
                    h22u(__halves2half2(__float2half(dt), __float2half(odt))));
                ptab[((size_t)l * TAB_ROWS + row0 + rr) * 64 + p] = v;
            }
        }
    }
}

// ---------------------------------------------------------------------------
// Conv with 4-way j-split.  grid: (512*4) x 256 = 8 blocks/CU = 32 waves/CU.
// Block (i, q) accumulates c-partials over j in [q*128, q*128+128).
// Lane layout: p2 = t&31 owns features 4p2..4p2+3; jc = t>>5 in [0,8)
// covers 16 j each (half the old serial chain per lane, 2x the waves/CU).
__global__ void __launch_bounds__(256, 8)
conv_kernel(const uint2* __restrict__ dpk, const unsigned* __restrict__ opk_in,
            const uint2* __restrict__ ptab, float* __restrict__ c_part, int l) {
    int bid = blockIdx.x;
    int i = bid >> 2;
    int q = bid & 3;
    int t = threadIdx.x;
    int p2 = t & 31;
    int jc = t >> 5;            // 0..7

    __shared__ __align__(16) uint2 ds[JPB];              // 1 KB
    __shared__ __align__(16) float redbuf[8 * 32 * 4];   // 4 KB

    if (t < JPB) ds[t] = dpk[i * N_ATOMS + q * JPB + t];
    __syncthreads();

    const char*  T  = (const char*)(ptab + (size_t)l * TAB_ROWS * 64) + p2 * 16;
    const uint2* ob = (const uint2*)opk_in + p2 + (size_t)(q * JPB) * 32;

    float4 acc = make_float4(0.0f, 0.0f, 0.0f, 0.0f);
    int j0 = jc * 16;
#pragma unroll 4
    for (int jj = 0; jj < 16; ++jj) {
        int j = j0 + jj;
        uint2 e = ds[j];                     // broadcast: uniform per half-wave
        uint4 tv = *(const uint4*)(T + e.x); // {t0 a, dt a, t0 b, dt b}
        uint2 ohu = ob[j * 32];              // features 4p2..4p2+3 of o_j
        __half2 fr2 = u2h2(e.y);
        __half2 wa = __hfma2(fr2, u2h2(tv.y), u2h2(tv.x));
        __half2 wb = __hfma2(fr2, u2h2(tv.w), u2h2(tv.z));
        __half2 oa = u2h2(ohu.x);
        __half2 obh = u2h2(ohu.y);
        acc.x = fmaf(__half2float(__low2half(wa)),  __half2float(__low2half(oa)),  acc.x);
        acc.y = fmaf(__half2float(__high2half(wa)), __half2float(__high2half(oa)), acc.y);
        acc.z = fmaf(__half2float(__low2half(wb)),  __half2float(__low2half(obh)), acc.z);
        acc.w = fmaf(__half2float(__high2half(wb)), __half2float(__high2half(obh)), acc.w);
    }
    *(float4*)&redbuf[(jc * 32 + p2) * 4] = acc;
    __syncthreads();
    if (t < 32) {
        float4 s = *(const float4*)&redbuf[t * 4];
#pragma unroll
        for (int qq = 1; qq < 8; ++qq) {
            float4 v = *(const float4*)&redbuf[(qq * 32 + t) * 4];
            s.x += v.x; s.y += v.y; s.z += v.z; s.w += v.w;
        }
        *(float4*)&c_part[((size_t)(i * JSPLIT + q)) * F_DIM + 4 * t] = s;
    }
}

// ---------------------------------------------------------------------------
// Node MLP (+ next atomwise / output head).  grid: 512 x 256.
__global__ void __launch_bounds__(256)
node_kernel(const float* __restrict__ c_part,
            const float* __restrict__ n_W1, const float* __restrict__ n_b1,
            const float* __restrict__ n_W2, const float* __restrict__ n_b2,
            float* __restrict__ h,
            const float* __restrict__ aw_W, const float* __restrict__ aw_b,
            unsigned* __restrict__ opk_out,
            const float* __restrict__ oW1, const float* __restrict__ ob1,
            const float* __restrict__ oW2, const float* __restrict__ ob2,
            float* __restrict__ out, int l) {
    int i = blockIdx.x;
    int t = threadIdx.x;

    __shared__ __align__(16) float cs[F_DIM];
    __shared__ __align__(16) float t1s[F_DIM];
    __shared__ __align__(16) float hs[F_DIM];
    __shared__ __align__(16) float redbuf[2 * F_DIM];

    if (t < F_DIM) {
        const float* cp = c_part + (size_t)i * JSPLIT * F_DIM + t;
        cs[t] = (cp[0] + cp[F_DIM]) + (cp[2 * F_DIM] + cp[3 * F_DIM]);
        hs[t] = h[i * F_DIM + t];
    }
    __syncthreads();

    // ---- phase A: t1s = ssp(cs @ W1 + b1), 2-way g-split ----
    {
        int q = t >> 7, f = t & 127;         // q in [0,2), 64 g each
        const float* W1 = n_W1 + l * F_DIM * F_DIM;
        float a = 0.0f;
        int g0 = q * 64;
        for (int g = 0; g < 64; ++g) a = fmaf(cs[g0 + g], W1[(g0 + g) * F_DIM + f], a);
        redbuf[q * F_DIM + f] = a;
    }
    __syncthreads();
    if (t < F_DIM)
        t1s[t] = ssp(redbuf[t] + redbuf[F_DIM + t] + n_b1[l * F_DIM + t]);
    __syncthreads();

    // ---- phase B: hs += t1s @ W2 + b2 ----
    {
        int q = t >> 7, f = t & 127;
        const float* W2 = n_W2 + l * F_DIM * F_DIM;
        float a = 0.0f;
        int g0 = q * 64;
        for (int g = 0; g < 64; ++g) a = fmaf(t1s[g0 + g], W2[(g0 + g) * F_DIM + f], a);
        redbuf[q * F_DIM + f] = a;
    }
    __syncthreads();
    if (t < F_DIM) {
        float hv = hs[t] + redbuf[t] + redbuf[F_DIM + t] + n_b2[l * F_DIM + t];
        hs[t] = hv;
        if (l < NLAYER - 1) h[i * F_DIM + t] = hv;
    }
    __syncthreads();

    if (l < NLAYER - 1) {
        // ---- phase C: next layer's atom-wise linear, packed half2 ----
        {
            int q = t >> 7, f = t & 127;
            const float* W = aw_W + (l + 1) * F_DIM * F_DIM;
            float a = 0.0f;
            int g0 = q * 64;
            for (int g = 0; g < 64; ++g) a = fmaf(hs[g0 + g], W[(g0 + g) * F_DIM + f], a);
            redbuf[q * F_DIM + f] = a;
        }
        __syncthreads();
        if (t < F_DIM) {
            t1s[t] = redbuf[t] + redbuf[F_DIM + t] + aw_b[(l + 1) * F_DIM + t];
        }
        __syncthreads();
        if (t < F_DIM / 2)
            opk_out[i * 64 + t] = h22u(__halves2half2(__float2half(t1s[2 * t]),
                                                      __float2half(t1s[2 * t + 1])));
    } else {
        // ---- output head: out[i] = ssp(hs @ oW1 + ob1) @ oW2 + ob2 ----
        {
            int q = t >> 5, f = t & 31;      // q in [0,8), 16 g each
            float a = 0.0f;
            int g0 = q * 16;
            for (int g = 0; g < 16; ++g) a = fmaf(hs[g0 + g], oW1[(g0 + g) * 32 + f], a);
            redbuf[q * 32 + f] = a;
        }
        __syncthreads();
        float val = 0.0f;
        if (t < 32) {
            float a = ob1[t];
#pragma unroll
            for (int q = 0; q < 8; ++q) a += redbuf[q * 32 + t];
            val = ssp(a) * oW2[t];
        }
#pragma unroll
        for (int off = 16; off > 0; off >>= 1) val += __shfl_xor(val, off, 64);
        if (t == 0) out[i] = val + ob2[0];
    }
}

// ---------------------------------------------------------------------------
extern "C" void kernel_launch(void* const* d_in, const int* in_sizes, int n_in,
                              void* d_out, int out_size, void* d_ws, size_t ws_size,
                              hipStream_t stream) {
    const int*   x     = (const int*)  d_in[0];
    const float* r     = (const float*)d_in[1];
    const float* emb   = (const float*)d_in[2];
    const float* aw_W  = (const float*)d_in[3];
    const float* aw_b  = (const float*)d_in[4];
    const float* cf_W1 = (const float*)d_in[5];
    const float* cf_b1 = (const float*)d_in[6];
    const float* cf_W2 = (const float*)d_in[7];
    const float* cf_b2 = (const float*)d_in[8];
    const float* n_W1  = (const float*)d_in[9];
    const float* n_b1  = (const float*)d_in[10];
    const float* n_W2  = (const float*)d_in[11];
    const float* n_b2  = (const float*)d_in[12];
    const float* oW1   = (const float*)d_in[13];
    const float* ob1   = (const float*)d_in[14];
    const float* oW2   = (const float*)d_in[15];
    const float* ob2   = (const float*)d_in[16];
    float* out = (float*)d_out;

    char* ws = (char*)d_ws;
    uint2*    dpk    = (uint2*)ws;    ws += (size_t)N_ATOMS * N_ATOMS * 8;       // 2 MB
    float*    h      = (float*)ws;    ws += (size_t)N_ATOMS * F_DIM * 4;         // 256 KB
    unsigned* opkA   = (unsigned*)ws; ws += (size_t)N_ATOMS * (F_DIM / 2) * 4;   // 128 KB
    unsigned* opkB   = (unsigned*)ws; ws += (size_t)N_ATOMS * (F_DIM / 2) * 4;   // 128 KB
    uint2*    ptab   = (uint2*)ws;    ws += (size_t)NLAYER * TAB_ROWS * 64 * 8;  // 2.7 MB
    float*    c_part = (float*)ws;                                               // 1 MB

    prep_build<<<N_ATOMS + NBBLK2, 256, 0, stream>>>(
        x, r, emb, aw_W, aw_b, cf_W1, cf_b1, cf_W2, cf_b2, dpk, h, opkA, ptab);
    for (int l = 0; l < NLAYER; ++l) {
        unsigned* oin  = (l & 1) ? opkB : opkA;
        unsigned* oout = (l & 1) ? opkA : opkB;
        conv_kernel<<<N_ATOMS * JSPLIT, 256, 0, stream>>>(dpk, oin, ptab, c_part, l);
        node_kernel<<<N_ATOMS, 256, 0, stream>>>(
            c_part, n_W1, n_b1, n_W2, n_b2, h, aw_W, aw_b, oout,
            oW1, ob1, oW2, ob2, out, l);
    }
}